// Round 1
// baseline (80.372 us; speedup 1.0000x reference)
//
#include <hip/hip_runtime.h>
#include <math.h>

// Problem constants (from reference)
#define B_    64
#define C_    8
#define T_    2048
#define K_    16
#define NF_   9
#define FEAT_ 144   // C_*NF_*2
#define MLP_  16
#define H1_   64
#define H2_   32
#define EFF_  60
#define W_    1988  // T_-EFF_
#define NWCH_ 8     // ceil(W_/256)

// Twiddles: angle(t) = 2*pi*t/16, t = (n*k) & 15; f[n] = sum win[k]*exp(-i*2*pi*n*k/16)
constexpr float COS16[16] = {
   1.0f,  0.92387953251128674f,  0.70710678118654752f,  0.38268343236508977f,
   0.0f, -0.38268343236508977f, -0.70710678118654752f, -0.92387953251128674f,
  -1.0f, -0.92387953251128674f, -0.70710678118654752f, -0.38268343236508977f,
   0.0f,  0.38268343236508977f,  0.70710678118654752f,  0.92387953251128674f };
constexpr float SIN16[16] = {
   0.0f,  0.38268343236508977f,  0.70710678118654752f,  0.92387953251128674f,
   1.0f,  0.92387953251128674f,  0.70710678118654752f,  0.38268343236508977f,
   0.0f, -0.38268343236508977f, -0.70710678118654752f, -0.92387953251128674f,
  -1.0f, -0.92387953251128674f, -0.70710678118654752f, -0.38268343236508977f };

// ---------------- Kernel 1: softmax weights over agg_w -> wts[W_] ----------------
__global__ __launch_bounds__(256) void softmax_kernel(const float* __restrict__ agg,
                                                      float* __restrict__ wts) {
  __shared__ float red[256];
  const int tid = threadIdx.x;
  float m = -INFINITY;
  for (int i = tid; i < W_; i += 256) m = fmaxf(m, agg[i]);
  red[tid] = m; __syncthreads();
  for (int s = 128; s > 0; s >>= 1) { if (tid < s) red[tid] = fmaxf(red[tid], red[tid+s]); __syncthreads(); }
  const float mx = red[0];
  __syncthreads();
  float sum = 0.f;
  for (int i = tid; i < W_; i += 256) sum += expf(agg[i] - mx);
  red[tid] = sum; __syncthreads();
  for (int s = 128; s > 0; s >>= 1) { if (tid < s) red[tid] += red[tid+s]; __syncthreads(); }
  const float inv = 1.f / red[0];
  for (int i = tid; i < W_; i += 256) wts[i] = expf(agg[i] - mx) * inv;
}

// ---------------- Kernel 2: fused window-DFT + feature + MLP + weighted partial sums ----------------
__global__ __launch_bounds__(256) void tcn_main(
    const float* __restrict__ x,
    const float* __restrict__ proj_w, const float* __restrict__ proj_b,
    const float* __restrict__ w1, const float* __restrict__ b1,
    const float* __restrict__ w2, const float* __restrict__ b2,
    const float* __restrict__ out_w, const float* __restrict__ out_b,
    const float* __restrict__ wts, float* __restrict__ partials) {
  // LDS-staged weights; PW transposed to [FEAT][MLP], W2 transposed to [H1][H2]
  __shared__ __align__(16) float PWt[FEAT_ * MLP_];
  __shared__ __align__(16) float W1s[H1_ * MLP_];
  __shared__ __align__(16) float W2t[H1_ * H2_];
  __shared__ float PBs[MLP_], B1s[H1_], B2s[H2_], OWs[H2_];
  __shared__ float red[256];

  const int tid = threadIdx.x;
  for (int idx = tid; idx < MLP_ * FEAT_; idx += 256) {
    const int j = idx / FEAT_, f = idx - j * FEAT_;   // proj_w[j][f]
    PWt[f * MLP_ + j] = proj_w[idx];
  }
  for (int idx = tid; idx < H1_ * MLP_; idx += 256) W1s[idx] = w1[idx];
  for (int idx = tid; idx < H2_ * H1_; idx += 256) {
    const int m = idx >> 6, i = idx & 63;             // w2[m][i]
    W2t[i * H2_ + m] = w2[idx];
  }
  if (tid < MLP_) PBs[tid] = proj_b[tid];
  if (tid < H1_) B1s[tid] = b1[tid];
  if (tid < H2_) { B2s[tid] = b2[tid]; OWs[tid] = out_w[tid]; }
  __syncthreads();

  const int b = blockIdx.y;
  const int w = blockIdx.x * 256 + tid;
  float val = 0.f;
  if (w < W_) {
    float pacc[MLP_];
    #pragma unroll
    for (int j = 0; j < MLP_; j++) pacc[j] = PBs[j];

    const float* xb = x + (size_t)(b * C_) * T_ + w;
    #pragma unroll 1
    for (int c = 0; c < C_; c++) {
      float win[K_];
      const float* xc = xb + c * T_;
      #pragma unroll
      for (int k = 0; k < K_; k++) win[k] = xc[k * 4];   // idx = w + 4k

      #pragma unroll
      for (int n = 0; n < NF_; n++) {
        float re = 0.f, im = 0.f;
        #pragma unroll
        for (int k = 0; k < K_; k++) {
          const int t = (n * k) & 15;
          re = fmaf(win[k],  COS16[t], re);
          im = fmaf(win[k], -SIN16[t], im);   // keeps +0.0 exactly when all sin terms are 0
        }
        const float mag = log1pf(sqrtf(fmaf(re, re, im * im)));
        const float ph  = atan2f(im, re) * 0.31830988618379067154f;  // 1/pi
        const int f0 = (c * NF_ + n) * 2;
        const float4* rm = reinterpret_cast<const float4*>(&PWt[f0 * MLP_]);
        const float4* rp = reinterpret_cast<const float4*>(&PWt[(f0 + 1) * MLP_]);
        #pragma unroll
        for (int q = 0; q < 4; q++) {
          const float4 a = rm[q], bb = rp[q];
          pacc[4*q+0] = fmaf(mag, a.x, pacc[4*q+0]);
          pacc[4*q+1] = fmaf(mag, a.y, pacc[4*q+1]);
          pacc[4*q+2] = fmaf(mag, a.z, pacc[4*q+2]);
          pacc[4*q+3] = fmaf(mag, a.w, pacc[4*q+3]);
          pacc[4*q+0] = fmaf(ph, bb.x, pacc[4*q+0]);
          pacc[4*q+1] = fmaf(ph, bb.y, pacc[4*q+1]);
          pacc[4*q+2] = fmaf(ph, bb.z, pacc[4*q+2]);
          pacc[4*q+3] = fmaf(ph, bb.w, pacc[4*q+3]);
        }
      }
    }

    float p[MLP_];
    #pragma unroll
    for (int j = 0; j < MLP_; j++) p[j] = tanhf(pacc[j]) * 3.14159265358979323846f;

    float h2a[H2_];
    #pragma unroll
    for (int m = 0; m < H2_; m++) h2a[m] = B2s[m];

    #pragma unroll 4
    for (int i = 0; i < H1_; i++) {
      const float4* r1 = reinterpret_cast<const float4*>(&W1s[i * MLP_]);
      float acc = B1s[i];
      #pragma unroll
      for (int q = 0; q < 4; q++) {
        const float4 a = r1[q];
        acc = fmaf(p[4*q+0], a.x, acc);
        acc = fmaf(p[4*q+1], a.y, acc);
        acc = fmaf(p[4*q+2], a.z, acc);
        acc = fmaf(p[4*q+3], a.w, acc);
      }
      const float h1v = fmaxf(acc, 0.f);
      const float4* r2 = reinterpret_cast<const float4*>(&W2t[i * H2_]);
      #pragma unroll
      for (int q = 0; q < 8; q++) {
        const float4 a = r2[q];
        h2a[4*q+0] = fmaf(h1v, a.x, h2a[4*q+0]);
        h2a[4*q+1] = fmaf(h1v, a.y, h2a[4*q+1]);
        h2a[4*q+2] = fmaf(h1v, a.z, h2a[4*q+2]);
        h2a[4*q+3] = fmaf(h1v, a.w, h2a[4*q+3]);
      }
    }

    float o = out_b[0];
    #pragma unroll
    for (int m = 0; m < H2_; m++) o = fmaf(fmaxf(h2a[m], 0.f), OWs[m], o);
    val = o * wts[w];
  }

  // deterministic block reduction of weighted outputs
  red[tid] = val; __syncthreads();
  for (int s = 128; s > 0; s >>= 1) { if (tid < s) red[tid] += red[tid+s]; __syncthreads(); }
  if (tid == 0) partials[b * gridDim.x + blockIdx.x] = red[0];
}

// ---------------- Kernel 3: fixed-order finalize ----------------
__global__ void finalize_kernel(const float* __restrict__ partials, float* __restrict__ out) {
  const int b = threadIdx.x;
  if (b < B_) {
    float s = 0.f;
    #pragma unroll
    for (int c = 0; c < NWCH_; c++) s += partials[b * NWCH_ + c];
    out[b] = s;
  }
}

extern "C" void kernel_launch(void* const* d_in, const int* in_sizes, int n_in,
                              void* d_out, int out_size, void* d_ws, size_t ws_size,
                              hipStream_t stream) {
  const float* x      = (const float*)d_in[0];
  const float* proj_w = (const float*)d_in[1];
  const float* proj_b = (const float*)d_in[2];
  const float* w1     = (const float*)d_in[3];
  const float* b1     = (const float*)d_in[4];
  const float* w2     = (const float*)d_in[5];
  const float* b2     = (const float*)d_in[6];
  const float* out_w  = (const float*)d_in[7];
  const float* out_b  = (const float*)d_in[8];
  const float* agg_w  = (const float*)d_in[9];

  float* wts      = (float*)d_ws;              // W_ floats
  float* partials = (float*)d_ws + 2048;       // B_*NWCH_ floats

  softmax_kernel<<<1, 256, 0, stream>>>(agg_w, wts);
  tcn_main<<<dim3(NWCH_, B_), 256, 0, stream>>>(x, proj_w, proj_b, w1, b1, w2, b2,
                                                out_w, out_b, wts, partials);
  finalize_kernel<<<1, 64, 0, stream>>>(partials, (float*)d_out);
}

// Round 2
// 60.713 us; speedup vs baseline: 1.3238x; 1.3238x over previous
//
#include <hip/hip_runtime.h>
#include <math.h>

// Problem constants (from reference)
#define B_    64
#define C_    8
#define T_    2048
#define K_    16
#define NF_   9
#define FEAT_ 144   // C_*NF_*2
#define MLP_  16
#define H1_   64
#define H2_   32
#define EFF_  60
#define W_    1988  // T_-EFF_
#define NWCH_ 8     // ceil(W_/256)
#define PI_F  3.14159265358979323846f

// Twiddles: angle(t) = 2*pi*t/16; f[n] = sum win[k]*exp(-i*2*pi*n*k/16)
constexpr float COS16[16] = {
   1.0f,  0.92387953251128674f,  0.70710678118654752f,  0.38268343236508977f,
   0.0f, -0.38268343236508977f, -0.70710678118654752f, -0.92387953251128674f,
  -1.0f, -0.92387953251128674f, -0.70710678118654752f, -0.38268343236508977f,
   0.0f,  0.38268343236508977f,  0.70710678118654752f,  0.92387953251128674f };
constexpr float SIN16[16] = {
   0.0f,  0.38268343236508977f,  0.70710678118654752f,  0.92387953251128674f,
   1.0f,  0.92387953251128674f,  0.70710678118654752f,  0.38268343236508977f,
   0.0f, -0.38268343236508977f, -0.70710678118654752f, -0.92387953251128674f,
   0.0f, -0.92387953251128674f, -0.70710678118654752f, -0.38268343236508977f };
// NOTE: SIN16[12] should be -1.0f; fixed below via corrected table:
constexpr float SIN16F[16] = {
   0.0f,  0.38268343236508977f,  0.70710678118654752f,  0.92387953251128674f,
   1.0f,  0.92387953251128674f,  0.70710678118654752f,  0.38268343236508977f,
   0.0f, -0.38268343236508977f, -0.70710678118654752f, -0.92387953251128674f,
  -1.0f, -0.92387953251128674f, -0.70710678118654752f, -0.38268343236508977f };

// ---- fast device math (hw transcendentals) ----
__device__ __forceinline__ float fast_log1p(float s) {
  // log(1+s) = log2(1+s)*ln2 ; abs err ~1e-7 for s>=0
  return __builtin_amdgcn_logf(1.0f + s) * 0.69314718055994531f;
}

__device__ __forceinline__ float atanpi_poly(float r) {
  // minimax odd poly for atan(r)/pi on [0,1]; coeffs = standard deg-11 set / pi
  const float s2 = r * r;
  float p = -0.0037310f;
  p = fmaf(p, s2,  0.0167600f);
  p = fmaf(p, s2, -0.0370617f);
  p = fmaf(p, s2,  0.0616068f);
  p = fmaf(p, s2, -0.10587734f);
  p = fmaf(p, s2,  0.31830265f);
  return r * p;
}

__device__ __forceinline__ float atan2pi_fast(float im, float re) {
  const float ax = fabsf(re), ay = fabsf(im);
  const float mx = fmaxf(ax, ay), mn = fminf(ax, ay);
  const float r = mn * __builtin_amdgcn_rcpf(fmaxf(mx, 1e-37f));
  float t = atanpi_poly(r);
  t = (ay > ax) ? 0.5f - t : t;
  t = (__float_as_uint(re) & 0x80000000u) ? 1.0f - t : t;  // signbit(re) -> pi - t (handles re=-0)
  return copysignf(t, im);                                  // im=+0 keeps +pi convention
}

__device__ __forceinline__ float fast_tanh(float z) {
  const float az = fabsf(z);
  const float e = __builtin_amdgcn_exp2f(-2.8853900817779268f * az);  // exp(-2|z|)
  const float th = fmaf(-2.0f, e * __builtin_amdgcn_rcpf(1.0f + e), 1.0f);
  return copysignf(th, z);
}

// ---------------- Kernel 0: transpose weights into workspace ----------------
// PWt[FEAT][MLP] (feature-major) and W2t[H1][H2] so scalar loads are contiguous rows.
__global__ __launch_bounds__(256) void prep_kernel(const float* __restrict__ pw,
                                                   const float* __restrict__ w2,
                                                   float* __restrict__ PWt,
                                                   float* __restrict__ W2t) {
  const int tid = blockIdx.x * 256 + threadIdx.x;
  if (tid < MLP_ * FEAT_) {
    const int j = tid / FEAT_, f = tid - j * FEAT_;  // pw[j][f]
    PWt[f * MLP_ + j] = pw[tid];
  }
  if (tid < H2_ * H1_) {
    const int m = tid >> 6, i = tid & 63;            // w2[m][i]
    W2t[i * H2_ + m] = w2[tid];
  }
}

// ---------------- Kernel 1: softmax weights over agg_w -> wts[W_] ----------------
__global__ __launch_bounds__(256) void softmax_kernel(const float* __restrict__ agg,
                                                      float* __restrict__ wts) {
  __shared__ float red[256];
  const int tid = threadIdx.x;
  float m = -INFINITY;
  for (int i = tid; i < W_; i += 256) m = fmaxf(m, agg[i]);
  red[tid] = m; __syncthreads();
  for (int s = 128; s > 0; s >>= 1) { if (tid < s) red[tid] = fmaxf(red[tid], red[tid+s]); __syncthreads(); }
  const float mx = red[0];
  __syncthreads();
  float sum = 0.f;
  for (int i = tid; i < W_; i += 256) sum += expf(agg[i] - mx);
  red[tid] = sum; __syncthreads();
  for (int s = 128; s > 0; s >>= 1) { if (tid < s) red[tid] += red[tid+s]; __syncthreads(); }
  const float inv = 1.f / red[0];
  for (int i = tid; i < W_; i += 256) wts[i] = expf(agg[i] - mx) * inv;
}

// ---------------- Kernel 2: fused DFT + feature + MLP + weighted partial sums ----------------
// Weights read through wave-uniform global addresses -> scalar (SMEM) loads, no LDS staging.
__global__ __launch_bounds__(256) void tcn_main(
    const float* __restrict__ x,
    const float* __restrict__ PWt, const float* __restrict__ proj_b,
    const float* __restrict__ w1, const float* __restrict__ b1,
    const float* __restrict__ W2t, const float* __restrict__ b2,
    const float* __restrict__ out_w, const float* __restrict__ out_b,
    const float* __restrict__ wts, float* __restrict__ partials) {
  __shared__ float red[256];
  const int tid = threadIdx.x;
  const int b = blockIdx.y;
  const int w = blockIdx.x * 256 + tid;
  float val = 0.f;
  if (w < W_) {
    float pacc[MLP_];
    #pragma unroll
    for (int j = 0; j < MLP_; j++) pacc[j] = proj_b[j];

    const float* xb = x + (size_t)(b * C_) * T_ + w;
    #pragma unroll 1
    for (int c = 0; c < C_; c++) {
      const float* xc = xb + c * T_;
      float win[K_];
      #pragma unroll
      for (int k = 0; k < K_; k++) win[k] = xc[k * 4];   // idx = w + 4k

      // even/odd fold: F[n] = sum_{k<8} (win[k] + (-1)^n win[k+8]) * T^{nk}
      float ae[8], bo[8];
      #pragma unroll
      for (int k = 0; k < 8; k++) { ae[k] = win[k] + win[k+8]; bo[k] = win[k] - win[k+8]; }

      #pragma unroll
      for (int n = 0; n < NF_; n++) {
        float re = 0.f, im = 0.f;
        #pragma unroll
        for (int k = 0; k < 8; k++) {
          const float v = (n & 1) ? bo[k] : ae[k];
          const int t = (n * k) & 15;
          re = fmaf(v,  COS16[t],  re);
          im = fmaf(v, -SIN16F[t], im);   // im stays +0.0 exactly for n=0,8
        }
        const float m2  = fmaf(re, re, im * im);
        const float s   = __builtin_amdgcn_sqrtf(m2);
        const float mag = fast_log1p(s);
        const float ph  = atan2pi_fast(im, re);

        const float* rm = PWt + (size_t)((c * NF_ + n) * 2) * MLP_;  // contiguous 32 floats
        #pragma unroll
        for (int j = 0; j < MLP_; j++)
          pacc[j] = fmaf(mag, rm[j], fmaf(ph, rm[MLP_ + j], pacc[j]));
      }
    }

    float p[MLP_];
    #pragma unroll
    for (int j = 0; j < MLP_; j++) p[j] = fast_tanh(pacc[j]) * PI_F;

    float h2a[H2_];
    #pragma unroll
    for (int m = 0; m < H2_; m++) h2a[m] = b2[m];

    #pragma unroll 8
    for (int i = 0; i < H1_; i++) {
      const float* r1 = w1 + i * MLP_;
      float acc = b1[i];
      #pragma unroll
      for (int j = 0; j < MLP_; j++) acc = fmaf(p[j], r1[j], acc);
      const float h1v = fmaxf(acc, 0.f);
      const float* r2 = W2t + i * H2_;
      #pragma unroll
      for (int m = 0; m < H2_; m++) h2a[m] = fmaf(h1v, r2[m], h2a[m]);
    }

    float o = out_b[0];
    #pragma unroll
    for (int m = 0; m < H2_; m++) o = fmaf(fmaxf(h2a[m], 0.f), out_w[m], o);
    val = o * wts[w];
  }

  // deterministic block reduction
  red[tid] = val; __syncthreads();
  for (int s = 128; s > 0; s >>= 1) { if (tid < s) red[tid] += red[tid+s]; __syncthreads(); }
  if (tid == 0) partials[b * gridDim.x + blockIdx.x] = red[0];
}

// ---------------- Kernel 3: fixed-order finalize ----------------
__global__ void finalize_kernel(const float* __restrict__ partials, float* __restrict__ out) {
  const int b = threadIdx.x;
  if (b < B_) {
    float s = 0.f;
    #pragma unroll
    for (int c = 0; c < NWCH_; c++) s += partials[b * NWCH_ + c];
    out[b] = s;
  }
}

extern "C" void kernel_launch(void* const* d_in, const int* in_sizes, int n_in,
                              void* d_out, int out_size, void* d_ws, size_t ws_size,
                              hipStream_t stream) {
  const float* x      = (const float*)d_in[0];
  const float* proj_w = (const float*)d_in[1];
  const float* proj_b = (const float*)d_in[2];
  const float* w1     = (const float*)d_in[3];
  const float* b1     = (const float*)d_in[4];
  const float* w2     = (const float*)d_in[5];
  const float* b2     = (const float*)d_in[6];
  const float* out_w  = (const float*)d_in[7];
  const float* out_b  = (const float*)d_in[8];
  const float* agg_w  = (const float*)d_in[9];

  float* wts      = (float*)d_ws;                    // W_ floats
  float* partials = (float*)d_ws + 2048;             // B_*NWCH_ floats
  float* PWt      = (float*)d_ws + 4096;             // FEAT_*MLP_ = 2304 floats
  float* W2t      = (float*)d_ws + 4096 + 2304;      // H1_*H2_ = 2048 floats

  prep_kernel<<<9, 256, 0, stream>>>(proj_w, w2, PWt, W2t);
  softmax_kernel<<<1, 256, 0, stream>>>(agg_w, wts);
  tcn_main<<<dim3(NWCH_, B_), 256, 0, stream>>>(x, PWt, proj_b, w1, b1, W2t, b2,
                                                out_w, out_b, wts, partials);
  finalize_kernel<<<1, 64, 0, stream>>>(partials, (float*)d_out);
}